// Round 13
// baseline (344.718 us; speedup 1.0000x reference)
//
#include <hip/hip_runtime.h>

#define NN 100000
#define C 128
#define VEC 16
#define AROW 136   // padded LDS row stride (ushorts)
#define GCAP 240000

typedef __bf16 bfx8 __attribute__((ext_vector_type(8)));
typedef float f32x4 __attribute__((ext_vector_type(4)));

__device__ inline unsigned pack_bf2(float a, float b) {
    unsigned ua = __float_as_uint(a);
    unsigned ub = __float_as_uint(b);
    ua = (ua + 0x7fffu + ((ua >> 16) & 1u)) >> 16;
    ub = (ub + 0x7fffu + ((ub >> 16) & 1u)) >> 16;
    return ua | (ub << 16);
}
__device__ inline unsigned short bf1(float a) {
    unsigned u = __float_as_uint(a);
    return (unsigned short)((u + 0x7fffu + ((u >> 16) & 1u)) >> 16);
}

// ---------------------------------------------------------------------------
// Prep: weight pre-swizzles (MFMA B-fragment bf16) + x -> bf16 cast.
// ---------------------------------------------------------------------------
__device__ inline void wconv_body(const float* __restrict__ W, unsigned short* __restrict__ Wf, int F) {
    int e = F & 7, l = (F >> 3) & 63, nt = (F >> 9) & 7, ks = (F >> 12) & 3, kt = F >> 14;
    int cin = ks * 32 + (l >> 4) * 8 + e;
    int cout = nt * 16 + (l & 15);
    Wf[F] = bf1(W[((size_t)kt * C + cin) * C + cout]);
}

__global__ __launch_bounds__(256) void prep(const float* __restrict__ v1w, const float* __restrict__ v2w,
                                            const float* __restrict__ outw, const float* __restrict__ x,
                                            unsigned short* __restrict__ v1f, unsigned short* __restrict__ v2f,
                                            unsigned short* __restrict__ outf, unsigned short* __restrict__ xh) {
    int b = blockIdx.x, tid = threadIdx.x;
    if (b < 1728)       wconv_body(v1w, v1f, b * 256 + tid);
    else if (b < 1792)  wconv_body(v2w, v2f, (b - 1728) * 256 + tid);
    else if (b < 1856)  wconv_body(outw, outf, (b - 1792) * 256 + tid);
    else {
        const int total8 = NN * C / 8;
        for (int t = (b - 1856) * 256 + tid; t < total8; t += 1024 * 256) {
            float4 xa = *reinterpret_cast<const float4*>(x + (size_t)t * 8);
            float4 xb = *reinterpret_cast<const float4*>(x + (size_t)t * 8 + 4);
            uint4 pk;
            pk.x = pack_bf2(xa.x, xa.y); pk.y = pack_bf2(xa.z, xa.w);
            pk.z = pack_bf2(xb.x, xb.y); pk.w = pack_bf2(xb.z, xb.w);
            *reinterpret_cast<uint4*>(&xh[(size_t)t * 8]) = pk;
        }
    }
}

// ---------------------------------------------------------------------------
// compactA: per-tap compacted pair lists. NO device fences (1323-block fence
// = L2 writeback storm, R9: +240us). Kernel boundary provides coherence.
// ---------------------------------------------------------------------------
__global__ __launch_bounds__(256) void compactA(const int* __restrict__ nbr, int* __restrict__ cnt,
                                                int* __restrict__ slotmap, int* __restrict__ pairs,
                                                unsigned* __restrict__ maskbuf) {
    const int k = blockIdx.x / 49, cb = blockIdx.x % 49, tid = threadIdx.x;
    const int i0 = cb * 2048 + tid * 8;
    int j[8]; int lc = 0;
#pragma unroll
    for (int t = 0; t < 8; ++t) {
        int i = i0 + t;
        j[t] = (i < NN) ? nbr[(size_t)k * NN + i] : -1;
        lc += (j[t] >= 0);
    }
    __shared__ int ls[256]; __shared__ int sbase;
    ls[tid] = lc; __syncthreads();
    for (int off = 1; off < 256; off <<= 1) {
        int v = (tid >= off) ? ls[tid - off] : 0;
        __syncthreads();
        ls[tid] += v;
        __syncthreads();
    }
    if (tid == 255) sbase = atomicAdd(&cnt[k], ls[255]);
    __syncthreads();
    int slot = sbase + ls[tid] - lc;
    for (int t = 0; t < 8; ++t) {
        int i = i0 + t; if (i >= NN) break;
        int s = -1;
        if (j[t] >= 0) {
            s = slot++;
            pairs[(size_t)k * NN + s] = j[t];
            atomicOr(&maskbuf[i], 1u << k);
        }
        slotmap[(size_t)k * NN + i] = s;
    }
}

__global__ void prefixA2(int* __restrict__ hdr) {
    if (threadIdx.x == 0) {
        int co = 0, go = 0;
        for (int k = 0; k < 27; ++k) {
            hdr[32 + k] = co; hdr[64 + k] = go;
            int nch = (hdr[k] + 31) / 32;
            co += nch; go += nch * 32;
        }
        hdr[32 + 27] = co;
    }
}

// ---------------------------------------------------------------------------
// convB: persistent per-tap dense GEMM over compacted 32-row chunks (xh bf16).
// ---------------------------------------------------------------------------
__global__ __launch_bounds__(256) void convB(const unsigned short* __restrict__ xh, const int* __restrict__ pairs,
                                             const int* __restrict__ hdr, const bfx8* __restrict__ Wf,
                                             unsigned short* __restrict__ g) {
    const int tid = threadIdx.x, l = tid & 63, w = tid >> 6, rr = tid >> 4, gg = tid & 15;
    __shared__ int sco[28], scnt[27], sgo[27];
    __shared__ unsigned short Ash[32 * AROW];
    __shared__ unsigned short Osh[32 * AROW];
    if (tid < 28) sco[tid] = hdr[32 + tid];
    if (tid < 27) { scnt[tid] = hdr[tid]; sgo[tid] = hdr[64 + tid]; }
    __syncthreads();
    const int tot = sco[27];
    for (int t = blockIdx.x; t < tot; t += gridDim.x) {
        int lo = 0, hi = 26;
        while (lo < hi) { int mid = (lo + hi + 1) >> 1; if (sco[mid] <= t) lo = mid; else hi = mid - 1; }
        const int k = lo, c = t - sco[k], cntk = scnt[k];
        const int srow = c * 32;
        const size_t gbase = (size_t)(sgo[k] + srow) * C;
#pragma unroll
        for (int h = 0; h < 2; ++h) {
            int row = srow + h * 16 + rr;
            uint4 pk = {0u, 0u, 0u, 0u};
            if (row < cntk) {
                int j = pairs[(size_t)k * NN + row];
                pk = *reinterpret_cast<const uint4*>(xh + (size_t)j * C + gg * 8);
            }
            *reinterpret_cast<uint4*>(&Ash[(h * 16 + rr) * AROW + gg * 8]) = pk;
        }
        __syncthreads();
        f32x4 a00 = {0.f,0.f,0.f,0.f}, a01 = {0.f,0.f,0.f,0.f};
        f32x4 a10 = {0.f,0.f,0.f,0.f}, a11 = {0.f,0.f,0.f,0.f};
        const unsigned short* ar0 = &Ash[(l & 15) * AROW + (l >> 4) * 8];
        const unsigned short* ar1 = &Ash[(16 + (l & 15)) * AROW + (l >> 4) * 8];
#pragma unroll
        for (int ks = 0; ks < 4; ++ks) {
            bfx8 b0 = Wf[((k * 4 + ks) * 8 + 2 * w) * 64 + l];
            bfx8 b1 = Wf[((k * 4 + ks) * 8 + 2 * w + 1) * 64 + l];
            bfx8 f0 = *reinterpret_cast<const bfx8*>(ar0 + ks * 32);
            bfx8 f1 = *reinterpret_cast<const bfx8*>(ar1 + ks * 32);
            a00 = __builtin_amdgcn_mfma_f32_16x16x32_bf16(f0, b0, a00, 0, 0, 0);
            a01 = __builtin_amdgcn_mfma_f32_16x16x32_bf16(f0, b1, a01, 0, 0, 0);
            a10 = __builtin_amdgcn_mfma_f32_16x16x32_bf16(f1, b0, a10, 0, 0, 0);
            a11 = __builtin_amdgcn_mfma_f32_16x16x32_bf16(f1, b1, a11, 0, 0, 0);
        }
#pragma unroll
        for (int r = 0; r < 4; ++r) {
            int row = (l >> 4) * 4 + r;
            Osh[row * AROW + w * 32 + (l & 15)]        = bf1(a00[r]);
            Osh[row * AROW + w * 32 + 16 + (l & 15)]   = bf1(a01[r]);
            Osh[(16 + row) * AROW + w * 32 + (l & 15)] = bf1(a10[r]);
            Osh[(16 + row) * AROW + w * 32 + 16 + (l & 15)] = bf1(a11[r]);
        }
        __syncthreads();
#pragma unroll
        for (int h = 0; h < 2; ++h) {
            int row = h * 16 + rr;
            uint4 v = *reinterpret_cast<uint4*>(&Osh[row * AROW + gg * 8]);
            *reinterpret_cast<uint4*>(&g[gbase + (size_t)row * C + gg * 8]) = v;
        }
        __syncthreads();
    }
}

// ---------------------------------------------------------------------------
// convC: out[i] = sum over valid taps of g rows (bf16 out) + fused BN stats.
// ---------------------------------------------------------------------------
__global__ __launch_bounds__(256) void convC(const unsigned short* __restrict__ g, const int* __restrict__ slotmap,
                                             const int* __restrict__ hdr, const unsigned* __restrict__ maskbuf,
                                             unsigned short* __restrict__ outh, float* __restrict__ psb,
                                             float* __restrict__ pqb) {
    const int tid = threadIdx.x, p = tid >> 4, gg = tid & 15, c0 = gg * 8;
    const int i = blockIdx.x * 16 + p;
    __shared__ int sgo[27];
    __shared__ float outt[16 * 132];
    if (tid < 27) sgo[tid] = hdr[64 + tid];
    __syncthreads();
    unsigned m = maskbuf[i];
    float acc[8] = {0.f,0.f,0.f,0.f,0.f,0.f,0.f,0.f};
    while (m) {
        int k = (int)__builtin_ctz(m); m &= m - 1;
        int slot = slotmap[(size_t)k * NN + i];
        const unsigned short* gr = &g[(size_t)(sgo[k] + slot) * C + c0];
        uint4 u = *reinterpret_cast<const uint4*>(gr);
        acc[0] += __uint_as_float(u.x << 16); acc[1] += __uint_as_float(u.x & 0xffff0000u);
        acc[2] += __uint_as_float(u.y << 16); acc[3] += __uint_as_float(u.y & 0xffff0000u);
        acc[4] += __uint_as_float(u.z << 16); acc[5] += __uint_as_float(u.z & 0xffff0000u);
        acc[6] += __uint_as_float(u.w << 16); acc[7] += __uint_as_float(u.w & 0xffff0000u);
    }
#pragma unroll
    for (int c2 = 0; c2 < 8; ++c2) outt[p * 132 + c0 + c2] = acc[c2];
    uint4 pk;
    pk.x = pack_bf2(acc[0], acc[1]); pk.y = pack_bf2(acc[2], acc[3]);
    pk.z = pack_bf2(acc[4], acc[5]); pk.w = pack_bf2(acc[6], acc[7]);
    *reinterpret_cast<uint4*>(&outh[(size_t)i * C + c0]) = pk;
    __syncthreads();
    if (tid < 128) {
        float s = 0.f, q = 0.f;
#pragma unroll
        for (int r = 0; r < 16; ++r) { float v = outt[r * 132 + tid]; s += v; q += v * v; }
        psb[(size_t)blockIdx.x * C + tid] = s;
        pqb[(size_t)blockIdx.x * C + tid] = q;
    }
}

// ---------------------------------------------------------------------------
// Fused BN stats (single kernel, 64 blocks, ticket last-block final).
// 64-block fences over ~3MB of partials are cheap; NOT at 1000+ blocks (R9).
// ---------------------------------------------------------------------------
__global__ __launch_bounds__(256) void statsF128(const float* __restrict__ psb, const float* __restrict__ pqb,
                                                 int rows,
                                                 float* __restrict__ ps2, float* __restrict__ pq2,
                                                 const float* __restrict__ g, const float* __restrict__ b,
                                                 float* __restrict__ a, float* __restrict__ cc,
                                                 int* __restrict__ ticket) {
    const int tid = threadIdx.x, ch = tid & 127, half = tid >> 7;
    float s = 0.f, q = 0.f;
    for (int i = blockIdx.x * 2 + half; i < rows; i += 128) {
        s += psb[(size_t)i * C + ch];
        q += pqb[(size_t)i * C + ch];
    }
    __shared__ float ls[256], lq[256];
    __shared__ int amlast;
    ls[tid] = s; lq[tid] = q;
    __syncthreads();
    if (tid < 128) {
        ps2[blockIdx.x * C + ch] = ls[tid] + ls[tid + 128];
        pq2[blockIdx.x * C + ch] = lq[tid] + lq[tid + 128];
    }
    __threadfence();
    __syncthreads();
    if (tid == 0) amlast = (atomicAdd(ticket, 1) == 63) ? 1 : 0;
    __syncthreads();
    if (!amlast) return;
    __threadfence();
    if (tid < 128) {
        float ss = 0.f, qq = 0.f;
        for (int i = 0; i < 64; ++i) { ss += ps2[i * C + ch]; qq += pq2[i * C + ch]; }
        float m = ss / (float)NN;
        float var = fmaxf(qq / (float)NN - m * m, 0.f);
        float rs = rsqrtf(var + 1e-5f);
        float av = g[ch] * rs;
        a[ch] = av;
        cc[ch] = b[ch] - m * av;
    }
}

__global__ __launch_bounds__(256) void statsF16(const float* __restrict__ buf,
                                                float* __restrict__ ps2, float* __restrict__ pq2,
                                                const float* __restrict__ g, const float* __restrict__ b,
                                                float* __restrict__ a, float* __restrict__ cc,
                                                int* __restrict__ ticket) {
    const int tid = threadIdx.x, ch = tid & 15, grp = tid >> 4;
    float s = 0.f, q = 0.f;
    for (int i = blockIdx.x * 16 + grp; i < NN; i += 64 * 16) {
        float val = buf[(size_t)i * VEC + ch];
        s += val; q += val * val;
    }
    __shared__ float ls[256], lq[256];
    __shared__ int amlast;
    ls[tid] = s; lq[tid] = q;
    __syncthreads();
    if (tid < 16) {
        float ss = 0.f, qq = 0.f;
        for (int g2 = 0; g2 < 16; ++g2) { ss += ls[g2 * 16 + ch]; qq += lq[g2 * 16 + ch]; }
        ps2[blockIdx.x * VEC + ch] = ss; pq2[blockIdx.x * VEC + ch] = qq;
    }
    __threadfence();
    __syncthreads();
    if (tid == 0) amlast = (atomicAdd(ticket, 1) == 63) ? 1 : 0;
    __syncthreads();
    if (!amlast) return;
    __threadfence();
    if (tid < 16) {
        float ss = 0.f, qq = 0.f;
        for (int i = 0; i < 64; ++i) { ss += ps2[i * VEC + ch]; qq += pq2[i * VEC + ch]; }
        float m = ss / (float)NN;
        float var = fmaxf(qq / (float)NN - m * m, 0.f);
        float rs = rsqrtf(var + 1e-5f);
        float av = g[ch] * rs;
        a[ch] = av;
        cc[ch] = b[ch] - m * av;
    }
}

// ---------------------------------------------------------------------------
// Dense bf16[N,128]@[128,128] MFMA matmul, 32-row tile, fused input BN+ReLU,
// bf16 output + fused fp32 BN partial stats on the output.
// ---------------------------------------------------------------------------
__global__ __launch_bounds__(256) void mm_bn_h32(const unsigned short* __restrict__ in,
                                                 const float* __restrict__ a,
                                                 const float* __restrict__ cc,
                                                 const bfx8* __restrict__ Wf,
                                                 unsigned short* __restrict__ out,
                                                 float* __restrict__ psb,
                                                 float* __restrict__ pqb) {
    const int tid = threadIdx.x, l = tid & 63, w = tid >> 6;
    const int rr = tid >> 4, gg = tid & 15;
    const size_t base = (size_t)blockIdx.x * 32;
    __shared__ unsigned short Ash[32 * AROW];
    __shared__ float outt[32 * 132];
    float4 a4 = *reinterpret_cast<const float4*>(&a[gg * 8]);
    float4 a4b = *reinterpret_cast<const float4*>(&a[gg * 8 + 4]);
    float4 c4 = *reinterpret_cast<const float4*>(&cc[gg * 8]);
    float4 c4b = *reinterpret_cast<const float4*>(&cc[gg * 8 + 4]);
#pragma unroll
    for (int h = 0; h < 2; ++h) {
        int row = h * 16 + rr;
        uint4 u = *reinterpret_cast<const uint4*>(in + (base + row) * C + gg * 8);
        float e0 = fmaxf(fmaf(__uint_as_float(u.x << 16),        a4.x,  c4.x), 0.f);
        float e1 = fmaxf(fmaf(__uint_as_float(u.x & 0xffff0000u), a4.y,  c4.y), 0.f);
        float e2 = fmaxf(fmaf(__uint_as_float(u.y << 16),        a4.z,  c4.z), 0.f);
        float e3 = fmaxf(fmaf(__uint_as_float(u.y & 0xffff0000u), a4.w,  c4.w), 0.f);
        float e4 = fmaxf(fmaf(__uint_as_float(u.z << 16),        a4b.x, c4b.x), 0.f);
        float e5 = fmaxf(fmaf(__uint_as_float(u.z & 0xffff0000u), a4b.y, c4b.y), 0.f);
        float e6 = fmaxf(fmaf(__uint_as_float(u.w << 16),        a4b.z, c4b.z), 0.f);
        float e7 = fmaxf(fmaf(__uint_as_float(u.w & 0xffff0000u), a4b.w, c4b.w), 0.f);
        u.x = pack_bf2(e0, e1); u.y = pack_bf2(e2, e3);
        u.z = pack_bf2(e4, e5); u.w = pack_bf2(e6, e7);
        *reinterpret_cast<uint4*>(&Ash[row * AROW + gg * 8]) = u;
    }
    __syncthreads();
    f32x4 a00 = {0.f,0.f,0.f,0.f}, a01 = {0.f,0.f,0.f,0.f};
    f32x4 a10 = {0.f,0.f,0.f,0.f}, a11 = {0.f,0.f,0.f,0.f};
    const unsigned short* ar0 = &Ash[(l & 15) * AROW + (l >> 4) * 8];
    const unsigned short* ar1 = &Ash[(16 + (l & 15)) * AROW + (l >> 4) * 8];
#pragma unroll
    for (int ks = 0; ks < 4; ++ks) {
        bfx8 b0 = Wf[(ks * 8 + 2 * w) * 64 + l];
        bfx8 b1 = Wf[(ks * 8 + 2 * w + 1) * 64 + l];
        bfx8 f0 = *reinterpret_cast<const bfx8*>(ar0 + ks * 32);
        bfx8 f1 = *reinterpret_cast<const bfx8*>(ar1 + ks * 32);
        a00 = __builtin_amdgcn_mfma_f32_16x16x32_bf16(f0, b0, a00, 0, 0, 0);
        a01 = __builtin_amdgcn_mfma_f32_16x16x32_bf16(f0, b1, a01, 0, 0, 0);
        a10 = __builtin_amdgcn_mfma_f32_16x16x32_bf16(f1, b0, a10, 0, 0, 0);
        a11 = __builtin_amdgcn_mfma_f32_16x16x32_bf16(f1, b1, a11, 0, 0, 0);
    }
#pragma unroll
    for (int r = 0; r < 4; ++r) {
        int row = (l >> 4) * 4 + r;
        outt[row * 132 + w * 32 + (l & 15)]        = a00[r];
        outt[row * 132 + w * 32 + 16 + (l & 15)]   = a01[r];
        outt[(16 + row) * 132 + w * 32 + (l & 15)] = a10[r];
        outt[(16 + row) * 132 + w * 32 + 16 + (l & 15)] = a11[r];
    }
    __syncthreads();
#pragma unroll
    for (int h = 0; h < 2; ++h) {
        int row = h * 16 + rr;
        float4 v0 = *reinterpret_cast<float4*>(&outt[row * 132 + gg * 8]);
        float4 v1 = *reinterpret_cast<float4*>(&outt[row * 132 + gg * 8 + 4]);
        uint4 pk;
        pk.x = pack_bf2(v0.x, v0.y); pk.y = pack_bf2(v0.z, v0.w);
        pk.z = pack_bf2(v1.x, v1.y); pk.w = pack_bf2(v1.z, v1.w);
        *reinterpret_cast<uint4*>(&out[(base + row) * C + gg * 8]) = pk;
    }
    if (tid < 128) {
        float s = 0.f, q = 0.f;
#pragma unroll
        for (int r = 0; r < 32; ++r) { float v = outt[r * 132 + tid]; s += v; q += v * v; }
        psb[(size_t)blockIdx.x * C + tid] = s;
        pqb[(size_t)blockIdx.x * C + tid] = q;
    }
}

// ---------------------------------------------------------------------------
// q = xh(bf16) @ q_w  ([N,128] @ [128,16]) fp32 accumulate
// ---------------------------------------------------------------------------
__global__ __launch_bounds__(256) void qmmh(const unsigned short* __restrict__ xh,
                                            const float* __restrict__ qw,
                                            float* __restrict__ outq) {
    const int v = threadIdx.x & 15, p = threadIdx.x >> 4;
    const size_t i = (size_t)blockIdx.x * 16 + p;
    float acc = 0.f;
    for (int cin0 = 0; cin0 < C; cin0 += 8) {
        uint4 u = *reinterpret_cast<const uint4*>(xh + i * C + cin0);
        acc += __uint_as_float(u.x << 16)         * qw[(cin0 + 0) * VEC + v]
             + __uint_as_float(u.x & 0xffff0000u) * qw[(cin0 + 1) * VEC + v]
             + __uint_as_float(u.y << 16)         * qw[(cin0 + 2) * VEC + v]
             + __uint_as_float(u.y & 0xffff0000u) * qw[(cin0 + 3) * VEC + v]
             + __uint_as_float(u.z << 16)         * qw[(cin0 + 4) * VEC + v]
             + __uint_as_float(u.z & 0xffff0000u) * qw[(cin0 + 5) * VEC + v]
             + __uint_as_float(u.w << 16)         * qw[(cin0 + 6) * VEC + v]
             + __uint_as_float(u.w & 0xffff0000u) * qw[(cin0 + 7) * VEC + v];
    }
    outq[i * VEC + v] = acc;
}

// ---------------------------------------------------------------------------
// Fused attention + OUTPUT 1x1 CONV: 16 points / 256 threads (best measured
// shape, R11). Segment compaction (48 threads, fixed per-expert segments
// [0,8)/[8,36)/[36,44), packed (k<<20)|j) replaces the serial 41-loop.
// raw[] aliases outt[] (disjoint lifetimes).
// ---------------------------------------------------------------------------
__global__ __launch_bounds__(256) void attn_out(const unsigned short* __restrict__ vraw,
                                                const float* __restrict__ a2,
                                                const float* __restrict__ c2,
                                                const float* __restrict__ qraw,
                                                const float* __restrict__ aq,
                                                const float* __restrict__ cq,
                                                const int* __restrict__ nA,
                                                const int* __restrict__ nB,
                                                const int* __restrict__ nC,
                                                const float* __restrict__ cb0,
                                                const float* __restrict__ cb1,
                                                const float* __restrict__ cb2,
                                                const bfx8* __restrict__ Wf,
                                                unsigned short* __restrict__ outh,
                                                float* __restrict__ psb,
                                                float* __restrict__ pqb) {
    const int tid = threadIdx.x, l = tid & 63, w = tid >> 6;
    const int base = blockIdx.x * 16;
    __shared__ float outt[16 * 132];          // phase A: raw idx; phase E: fp32 out
    int* raw = (int*)outt;                    // raw[p*41+k], 2624B < 8448B
    __shared__ int sjk[16][44];               // (k<<20)|j per expert segment
    __shared__ short sb[16][4];
    __shared__ float sattn[16][16][3];
    __shared__ unsigned short Ash[16 * AROW];

    for (int t = tid; t < 656; t += 256) {
        int k = t >> 4, p = t & 15;
        int i = base + p;
        int j;
        if (k < 7)       j = nA[(size_t)k * NN + i];
        else if (k < 34) j = nB[(size_t)(k - 7) * NN + i];
        else             j = nC[(size_t)(k - 34) * NN + i];
        raw[p * 41 + k] = j;
    }
    __syncthreads();
    if (tid < 48) {   // 16 points x 3 experts, independent fixed segments
        int p = tid & 15, e = tid >> 4;
        int k0 = (e == 0) ? 0 : ((e == 1) ? 7 : 34);
        int k1 = (e == 0) ? 7 : ((e == 1) ? 34 : 41);
        int segbase = (e == 0) ? 0 : ((e == 1) ? 8 : 36);
        int n = 0;
        for (int k = k0; k < k1; ++k) {
            int j = raw[p * 41 + k];
            if (j >= 0) { sjk[p][segbase + n] = ((k - k0) << 20) | j; ++n; }
        }
        sb[p][e] = (short)n;
    }
    __syncthreads();
    {   // scores + softmax: 16p x 16v, q-BN inline
        int p = tid >> 4, v = tid & 15;
        int n0 = sb[p][0], n1 = sb[p][1], n2 = sb[p][2];
        float av = aq[v], cv = cq[v];
        float qi = fmaxf(fmaf(qraw[(size_t)(base + p) * VEC + v], av, cv), 0.f);
        float a0 = 0.f, a1 = 0.f, a2s = 0.f;
        for (int s = 0; s < n0; ++s)       a0  += fmaxf(fmaf(qraw[(size_t)(sjk[p][s] & 0xFFFFF) * VEC + v], av, cv), 0.f);
        for (int s = 8; s < 8 + n1; ++s)   a1  += fmaxf(fmaf(qraw[(size_t)(sjk[p][s] & 0xFFFFF) * VEC + v], av, cv), 0.f);
        for (int s = 36; s < 36 + n2; ++s) a2s += fmaxf(fmaf(qraw[(size_t)(sjk[p][s] & 0xFFFFF) * VEC + v], av, cv), 0.f);
        float s0 = qi * a0 / (float)(n0 > 0 ? n0 : 1);
        float s1 = qi * a1 / (float)(n1 > 0 ? n1 : 1);
        float s2 = qi * a2s / (float)(n2 > 0 ? n2 : 1);
        float mx = fmaxf(s0, fmaxf(s1, s2));
        float e0 = __expf(s0 - mx), e1 = __expf(s1 - mx), e2 = __expf(s2 - mx);
        float inv = 1.f / (e0 + e1 + e2);
        sattn[p][v][0] = e0 * inv; sattn[p][v][1] = e1 * inv; sattn[p][v][2] = e2 * inv;
    }
    __syncthreads();
    {   // channelwise mix: 16p x 16 lanes x 8 ch, v-BN inline, static acc arrays
        int p = tid >> 4, g = tid & 15, c0 = g * 8;
        int n0 = sb[p][0], n1 = sb[p][1], n2 = sb[p][2];
        float4 va = *reinterpret_cast<const float4*>(&a2[c0]);
        float4 vab = *reinterpret_cast<const float4*>(&a2[c0 + 4]);
        float4 vc = *reinterpret_cast<const float4*>(&c2[c0]);
        float4 vcb = *reinterpret_cast<const float4*>(&c2[c0 + 4]);
        float A0[8], A1[8], A2[8];
#pragma unroll
        for (int c = 0; c < 8; ++c) { A0[c] = 0.f; A1[c] = 0.f; A2[c] = 0.f; }
        for (int s = 0; s < n0; ++s) {
            int jk = sjk[p][s]; int j = jk & 0xFFFFF, k = jk >> 20;
            uint4 u = *reinterpret_cast<const uint4*>(vraw + (size_t)j * C + c0);
            float4 ca = *reinterpret_cast<const float4*>(&cb0[k * C + c0]);
            float4 cb = *reinterpret_cast<const float4*>(&cb0[k * C + c0 + 4]);
            A0[0] = fmaf(ca.x, fmaxf(fmaf(__uint_as_float(u.x << 16),        va.x,  vc.x), 0.f), A0[0]);
            A0[1] = fmaf(ca.y, fmaxf(fmaf(__uint_as_float(u.x & 0xffff0000u), va.y,  vc.y), 0.f), A0[1]);
            A0[2] = fmaf(ca.z, fmaxf(fmaf(__uint_as_float(u.y << 16),        va.z,  vc.z), 0.f), A0[2]);
            A0[3] = fmaf(ca.w, fmaxf(fmaf(__uint_as_float(u.y & 0xffff0000u), va.w,  vc.w), 0.f), A0[3]);
            A0[4] = fmaf(cb.x, fmaxf(fmaf(__uint_as_float(u.z << 16),        vab.x, vcb.x), 0.f), A0[4]);
            A0[5] = fmaf(cb.y, fmaxf(fmaf(__uint_as_float(u.z & 0xffff0000u), vab.y, vcb.y), 0.f), A0[5]);
            A0[6] = fmaf(cb.z, fmaxf(fmaf(__uint_as_float(u.w << 16),        vab.z, vcb.z), 0.f), A0[6]);
            A0[7] = fmaf(cb.w, fmaxf(fmaf(__uint_as_float(u.w & 0xffff0000u), vab.w, vcb.w), 0.f), A0[7]);
        }
        for (int s = 8; s < 8 + n1; ++s) {
            int jk = sjk[p][s]; int j = jk & 0xFFFFF, k = jk >> 20;
            uint4 u = *reinterpret_cast<const uint4*>(vraw + (size_t)j * C + c0);
            float4 ca = *reinterpret_cast<const float4*>(&cb1[k * C + c0]);
            float4 cb = *reinterpret_cast<const float4*>(&cb1[k * C + c0 + 4]);
            A1[0] = fmaf(ca.x, fmaxf(fmaf(__uint_as_float(u.x << 16),        va.x,  vc.x), 0.f), A1[0]);
            A1[1] = fmaf(ca.y, fmaxf(fmaf(__uint_as_float(u.x & 0xffff0000u), va.y,  vc.y), 0.f), A1[1]);
            A1[2] = fmaf(ca.z, fmaxf(fmaf(__uint_as_float(u.y << 16),        va.z,  vc.z), 0.f), A1[2]);
            A1[3] = fmaf(ca.w, fmaxf(fmaf(__uint_as_float(u.y & 0xffff0000u), va.w,  vc.w), 0.f), A1[3]);
            A1[4] = fmaf(cb.x, fmaxf(fmaf(__uint_as_float(u.z << 16),        vab.x, vcb.x), 0.f), A1[4]);
            A1[5] = fmaf(cb.y, fmaxf(fmaf(__uint_as_float(u.z & 0xffff0000u), vab.y, vcb.y), 0.f), A1[5]);
            A1[6] = fmaf(cb.z, fmaxf(fmaf(__uint_as_float(u.w << 16),        vab.z, vcb.z), 0.f), A1[6]);
            A1[7] = fmaf(cb.w, fmaxf(fmaf(__uint_as_float(u.w & 0xffff0000u), vab.w, vcb.w), 0.f), A1[7]);
        }
        for (int s = 36; s < 36 + n2; ++s) {
            int jk = sjk[p][s]; int j = jk & 0xFFFFF, k = jk >> 20;
            uint4 u = *reinterpret_cast<const uint4*>(vraw + (size_t)j * C + c0);
            float4 ca = *reinterpret_cast<const float4*>(&cb2[k * C + c0]);
            float4 cb = *reinterpret_cast<const float4*>(&cb2[k * C + c0 + 4]);
            A2[0] = fmaf(ca.x, fmaxf(fmaf(__uint_as_float(u.x << 16),        va.x,  vc.x), 0.f), A2[0]);
            A2[1] = fmaf(ca.y, fmaxf(fmaf(__uint_as_float(u.x & 0xffff0000u), va.y,  vc.y), 0.f), A2[1]);
            A2[2] = fmaf(ca.z, fmaxf(fmaf(__uint_as_float(u.y << 16),        va.z,  vc.z), 0.f), A2[2]);
            A2[3] = fmaf(ca.w, fmaxf(fmaf(__uint_as_float(u.y & 0xffff0000u), va.w,  vc.w), 0.f), A2[3]);
            A2[4] = fmaf(cb.x, fmaxf(fmaf(__uint_as_float(u.z << 16),        vab.x, vcb.x), 0.f), A2[4]);
            A2[5] = fmaf(cb.y, fmaxf(fmaf(__uint_as_float(u.z & 0xffff0000u), vab.y, vcb.y), 0.f), A2[5]);
            A2[6] = fmaf(cb.z, fmaxf(fmaf(__uint_as_float(u.w << 16),        vab.z, vcb.z), 0.f), A2[6]);
            A2[7] = fmaf(cb.w, fmaxf(fmaf(__uint_as_float(u.w & 0xffff0000u), vab.w, vcb.w), 0.f), A2[7]);
        }
        float w0 = sattn[p][g][0], w1 = sattn[p][g][1], w2 = sattn[p][g][2];
        float o[8];
#pragma unroll
        for (int c = 0; c < 8; ++c) o[c] = w0 * A0[c] + w1 * A1[c] + w2 * A2[c];
        uint4 pk;
        pk.x = pack_bf2(o[0], o[1]); pk.y = pack_bf2(o[2], o[3]);
        pk.z = pack_bf2(o[4], o[5]); pk.w = pack_bf2(o[6], o[7]);
        *reinterpret_cast<uint4*>(&Ash[p * AROW + c0]) = pk;   // stage mix tile
    }
    __syncthreads();   // raw done; outt reused below
    // output 1x1 conv: 16-row MFMA tile against outf
    {
        f32x4 acc0 = {0.f, 0.f, 0.f, 0.f};
        f32x4 acc1 = {0.f, 0.f, 0.f, 0.f};
        const unsigned short* arow = &Ash[(l & 15) * AROW + (l >> 4) * 8];
#pragma unroll
        for (int ks = 0; ks < 4; ++ks) {
            bfx8 af = *reinterpret_cast<const bfx8*>(arow + ks * 32);
            bfx8 b0 = Wf[(ks * 8 + 2 * w) * 64 + l];
            bfx8 b1 = Wf[(ks * 8 + 2 * w + 1) * 64 + l];
            acc0 = __builtin_amdgcn_mfma_f32_16x16x32_bf16(af, b0, acc0, 0, 0, 0);
            acc1 = __builtin_amdgcn_mfma_f32_16x16x32_bf16(af, b1, acc1, 0, 0, 0);
        }
#pragma unroll
        for (int r = 0; r < 4; ++r) {
            int row = (l >> 4) * 4 + r;
            outt[row * 132 + w * 32 + (l & 15)] = acc0[r];
            outt[row * 132 + w * 32 + 16 + (l & 15)] = acc1[r];
        }
    }
    __syncthreads();
    {
        int rr = tid >> 4, gg = tid & 15;
        float4 v0 = *reinterpret_cast<float4*>(&outt[rr * 132 + gg * 8]);
        float4 v1 = *reinterpret_cast<float4*>(&outt[rr * 132 + gg * 8 + 4]);
        uint4 pk;
        pk.x = pack_bf2(v0.x, v0.y); pk.y = pack_bf2(v0.z, v0.w);
        pk.z = pack_bf2(v1.x, v1.y); pk.w = pack_bf2(v1.z, v1.w);
        *reinterpret_cast<uint4*>(&outh[(size_t)(base + rr) * C + gg * 8]) = pk;
    }
    if (tid < 128) {
        float s = 0.f, q = 0.f;
#pragma unroll
        for (int r = 0; r < 16; ++r) { float v = outt[r * 132 + tid]; s += v; q += v * v; }
        psb[(size_t)blockIdx.x * C + tid] = s;
        pqb[(size_t)blockIdx.x * C + tid] = q;
    }
}

// out = relu(bf16buf*a + c) + xh   (fp32 out, bf16 residual read)
__global__ __launch_bounds__(256) void final_bn_res_h(const unsigned short* __restrict__ buf,
                                                      const float* __restrict__ a,
                                                      const float* __restrict__ cc,
                                                      const unsigned short* __restrict__ xh,
                                                      float* __restrict__ out) {
    const int total8 = NN * C / 8;
    for (int t = blockIdx.x * 256 + threadIdx.x; t < total8; t += gridDim.x * 256) {
        int ch = (t * 8) & 127;
        uint4 u = *reinterpret_cast<const uint4*>(buf + (size_t)t * 8);
        uint4 xu = *reinterpret_cast<const uint4*>(xh + (size_t)t * 8);
        float4 a4 = *reinterpret_cast<const float4*>(&a[ch]);
        float4 a4b = *reinterpret_cast<const float4*>(&a[ch + 4]);
        float4 c4 = *reinterpret_cast<const float4*>(&cc[ch]);
        float4 c4b = *reinterpret_cast<const float4*>(&cc[ch + 4]);
        float4 o0, o1;
        o0.x = fmaxf(fmaf(__uint_as_float(u.x << 16),        a4.x,  c4.x), 0.f) + __uint_as_float(xu.x << 16);
        o0.y = fmaxf(fmaf(__uint_as_float(u.x & 0xffff0000u), a4.y,  c4.y), 0.f) + __uint_as_float(xu.x & 0xffff0000u);
        o0.z = fmaxf(fmaf(__uint_as_float(u.y << 16),        a4.z,  c4.z), 0.f) + __uint_as_float(xu.y << 16);
        o0.w = fmaxf(fmaf(__uint_as_float(u.y & 0xffff0000u), a4.w,  c4.w), 0.f) + __uint_as_float(xu.y & 0xffff0000u);
        o1.x = fmaxf(fmaf(__uint_as_float(u.z << 16),        a4b.x, c4b.x), 0.f) + __uint_as_float(xu.z << 16);
        o1.y = fmaxf(fmaf(__uint_as_float(u.z & 0xffff0000u), a4b.y, c4b.y), 0.f) + __uint_as_float(xu.z & 0xffff0000u);
        o1.z = fmaxf(fmaf(__uint_as_float(u.w << 16),        a4b.z, c4b.z), 0.f) + __uint_as_float(xu.w << 16);
        o1.w = fmaxf(fmaf(__uint_as_float(u.w & 0xffff0000u), a4b.w, c4b.w), 0.f) + __uint_as_float(xu.w & 0xffff0000u);
        *reinterpret_cast<float4*>(out + (size_t)t * 8) = o0;
        *reinterpret_cast<float4*>(out + (size_t)t * 8 + 4) = o1;
    }
}

extern "C" void kernel_launch(void* const* d_in, const int* in_sizes, int n_in,
                              void* d_out, int out_size, void* d_ws, size_t ws_size,
                              hipStream_t stream) {
    (void)in_sizes; (void)n_in; (void)out_size; (void)ws_size;
    const float* x    = (const float*)d_in[0];
    const float* v1_w = (const float*)d_in[1];
    const float* v1_g = (const float*)d_in[2];
    const float* v1_b = (const float*)d_in[3];
    const float* v2_w = (const float*)d_in[4];
    const float* v2_g = (const float*)d_in[5];
    const float* v2_b = (const float*)d_in[6];
    const float* q_w  = (const float*)d_in[7];
    const float* q_g  = (const float*)d_in[8];
    const float* q_b  = (const float*)d_in[9];
    const float* cb0  = (const float*)d_in[10];
    const float* cb1  = (const float*)d_in[11];
    const float* cb2  = (const float*)d_in[12];
    const float* out_w = (const float*)d_in[13];
    const float* out_g = (const float*)d_in[14];
    const float* out_b = (const float*)d_in[15];
    const int* nbrA = (const int*)d_in[16];   // cross2, K=7
    const int* nbrB = (const int*)d_in[17];   // cube,  K=27
    const int* nbrC = (const int*)d_in[18];   // cross3, K=7
    float* out = (float*)d_out;

    float* w = (float*)d_ws;
    unsigned short* bufAh = (unsigned short*)w;                // NN*C ushorts
    float* r1 = w + (size_t)NN * C / 2;
    // region1 (conv-stage) aliased by later {bufBh, bufQ}:
    unsigned short* g = (unsigned short*)r1;                   // GCAP*C ushorts
    int* slotmap = (int*)(r1 + 15360000);
    int* pairs   = (int*)(r1 + 15360000 + 2700000);
    unsigned short* bufBh = (unsigned short*)r1;               // NN*C ushorts
    float* bufQ = r1 + 6400000;                                // NN*VEC floats
    size_t o = (size_t)NN * C / 2 + 20760000;
    unsigned short* xh = (unsigned short*)(w + o); o += (size_t)NN * C / 2;
    float* psb  = w + o; o += (size_t)6250 * C;
    float* pqb  = w + o; o += (size_t)6250 * C;
    float* ps2  = w + o; o += 64 * C;
    float* pq2  = w + o; o += 64 * C;
    float* ps16 = w + o; o += 64 * VEC;
    float* pq16 = w + o; o += 64 * VEC;
    float* a1 = w + o; o += C;  float* c1 = w + o; o += C;
    float* a2 = w + o; o += C;  float* c2 = w + o; o += C;
    float* ao = w + o; o += C;  float* co = w + o; o += C;
    float* aq = w + o; o += VEC; float* cq = w + o; o += VEC;
    unsigned short* v1f = (unsigned short*)(w + o); o += (27 * 16384) / 2;
    unsigned short* v2f = (unsigned short*)(w + o); o += 16384 / 2;
    unsigned short* outf = (unsigned short*)(w + o); o += 16384 / 2;
    int* hdr = (int*)(w + o); o += 128;      // [96..99] = stat tickets
    unsigned* maskbuf = (unsigned*)(w + o); o += NN;

    hipMemsetAsync(hdr, 0, (size_t)(128 + NN) * sizeof(int), stream);
    prep<<<2880, 256, 0, stream>>>(v1_w, v2_w, out_w, x, v1f, v2f, outf, xh);

    // conv1 (cube-27): compaction + prefix + dense GEMM + scatter-sum
    compactA<<<27 * 49, 256, 0, stream>>>(nbrB, hdr, slotmap, pairs, maskbuf);
    prefixA2<<<1, 64, 0, stream>>>(hdr);
    convB<<<2048, 256, 0, stream>>>(xh, pairs, hdr, (const bfx8*)v1f, g);
    convC<<<NN / 16, 256, 0, stream>>>(g, slotmap, hdr, maskbuf, bufAh, psb, pqb);
    statsF128<<<64, 256, 0, stream>>>(psb, pqb, 6250, ps2, pq2, v1_g, v1_b, a1, c1, hdr + 96);

    // v2 1x1 conv (fused input BN+ReLU) -> bufBh raw (g/slotmap/pairs dead)
    mm_bn_h32<<<NN / 32, 256, 0, stream>>>(bufAh, a1, c1, (const bfx8*)v2f, bufBh, psb, pqb);
    statsF128<<<64, 256, 0, stream>>>(psb, pqb, 3125, ps2, pq2, v2_g, v2_b, a2, c2, hdr + 97);

    // query branch (bf16 x input; BN fused into attn)
    qmmh<<<NN / 16, 256, 0, stream>>>(xh, q_w, bufQ);
    statsF16<<<64, 256, 0, stream>>>(bufQ, ps16, pq16, q_g, q_b, aq, cq, hdr + 98);

    // fused expert convs + attention mix + OUTPUT 1x1 conv -> bufAh raw
    attn_out<<<NN / 16, 256, 0, stream>>>(bufBh, a2, c2, bufQ, aq, cq,
                                          nbrA, nbrB, nbrC, cb0, cb1, cb2,
                                          (const bfx8*)outf, bufAh, psb, pqb);
    statsF128<<<64, 256, 0, stream>>>(psb, pqb, 6250, ps2, pq2, out_g, out_b, ao, co, hdr + 99);

    // final BN + residual (bf16 residual read)
    final_bn_res_h<<<2048, 256, 0, stream>>>(bufAh, ao, co, xh, out);
}

// Round 14
// 330.837 us; speedup vs baseline: 1.0420x; 1.0420x over previous
//
#include <hip/hip_runtime.h>

#define NN 100000
#define C 128
#define VEC 16
#define AROW 136   // padded LDS row stride (ushorts)
#define GCAP 240000

typedef __bf16 bfx8 __attribute__((ext_vector_type(8)));
typedef float f32x4 __attribute__((ext_vector_type(4)));

__device__ inline unsigned pack_bf2(float a, float b) {
    unsigned ua = __float_as_uint(a);
    unsigned ub = __float_as_uint(b);
    ua = (ua + 0x7fffu + ((ua >> 16) & 1u)) >> 16;
    ub = (ub + 0x7fffu + ((ub >> 16) & 1u)) >> 16;
    return ua | (ub << 16);
}
__device__ inline unsigned short bf1(float a) {
    unsigned u = __float_as_uint(a);
    return (unsigned short)((u + 0x7fffu + ((u >> 16) & 1u)) >> 16);
}

// ---------------------------------------------------------------------------
// Prep: weight pre-swizzles (MFMA B-fragment bf16) + x -> bf16 cast.
// ---------------------------------------------------------------------------
__device__ inline void wconv_body(const float* __restrict__ W, unsigned short* __restrict__ Wf, int F) {
    int e = F & 7, l = (F >> 3) & 63, nt = (F >> 9) & 7, ks = (F >> 12) & 3, kt = F >> 14;
    int cin = ks * 32 + (l >> 4) * 8 + e;
    int cout = nt * 16 + (l & 15);
    Wf[F] = bf1(W[((size_t)kt * C + cin) * C + cout]);
}

__global__ __launch_bounds__(256) void prep(const float* __restrict__ v1w, const float* __restrict__ v2w,
                                            const float* __restrict__ outw, const float* __restrict__ x,
                                            unsigned short* __restrict__ v1f, unsigned short* __restrict__ v2f,
                                            unsigned short* __restrict__ outf, unsigned short* __restrict__ xh) {
    int b = blockIdx.x, tid = threadIdx.x;
    if (b < 1728)       wconv_body(v1w, v1f, b * 256 + tid);
    else if (b < 1792)  wconv_body(v2w, v2f, (b - 1728) * 256 + tid);
    else if (b < 1856)  wconv_body(outw, outf, (b - 1792) * 256 + tid);
    else {
        const int total8 = NN * C / 8;
        for (int t = (b - 1856) * 256 + tid; t < total8; t += 1024 * 256) {
            float4 xa = *reinterpret_cast<const float4*>(x + (size_t)t * 8);
            float4 xb = *reinterpret_cast<const float4*>(x + (size_t)t * 8 + 4);
            uint4 pk;
            pk.x = pack_bf2(xa.x, xa.y); pk.y = pack_bf2(xa.z, xa.w);
            pk.z = pack_bf2(xb.x, xb.y); pk.w = pack_bf2(xb.z, xb.w);
            *reinterpret_cast<uint4*>(&xh[(size_t)t * 8]) = pk;
        }
    }
}

// ---------------------------------------------------------------------------
// compactA: per-tap compacted pair lists. NO device fences (1323-block fence
// = L2 writeback storm, R9: +240us). Kernel boundary provides coherence.
// ---------------------------------------------------------------------------
__global__ __launch_bounds__(256) void compactA(const int* __restrict__ nbr, int* __restrict__ cnt,
                                                int* __restrict__ slotmap, int* __restrict__ pairs,
                                                unsigned* __restrict__ maskbuf) {
    const int k = blockIdx.x / 49, cb = blockIdx.x % 49, tid = threadIdx.x;
    const int i0 = cb * 2048 + tid * 8;
    int j[8]; int lc = 0;
#pragma unroll
    for (int t = 0; t < 8; ++t) {
        int i = i0 + t;
        j[t] = (i < NN) ? nbr[(size_t)k * NN + i] : -1;
        lc += (j[t] >= 0);
    }
    __shared__ int ls[256]; __shared__ int sbase;
    ls[tid] = lc; __syncthreads();
    for (int off = 1; off < 256; off <<= 1) {
        int v = (tid >= off) ? ls[tid - off] : 0;
        __syncthreads();
        ls[tid] += v;
        __syncthreads();
    }
    if (tid == 255) sbase = atomicAdd(&cnt[k], ls[255]);
    __syncthreads();
    int slot = sbase + ls[tid] - lc;
    for (int t = 0; t < 8; ++t) {
        int i = i0 + t; if (i >= NN) break;
        int s = -1;
        if (j[t] >= 0) {
            s = slot++;
            pairs[(size_t)k * NN + s] = j[t];
            atomicOr(&maskbuf[i], 1u << k);
        }
        slotmap[(size_t)k * NN + i] = s;
    }
}

__global__ void prefixA2(int* __restrict__ hdr) {
    if (threadIdx.x == 0) {
        int co = 0, go = 0;
        for (int k = 0; k < 27; ++k) {
            hdr[32 + k] = co; hdr[64 + k] = go;
            int nch = (hdr[k] + 31) / 32;
            co += nch; go += nch * 32;
        }
        hdr[32 + 27] = co;
    }
}

// ---------------------------------------------------------------------------
// convB: persistent per-tap dense GEMM over compacted 32-row chunks (xh bf16).
// ---------------------------------------------------------------------------
__global__ __launch_bounds__(256) void convB(const unsigned short* __restrict__ xh, const int* __restrict__ pairs,
                                             const int* __restrict__ hdr, const bfx8* __restrict__ Wf,
                                             unsigned short* __restrict__ g) {
    const int tid = threadIdx.x, l = tid & 63, w = tid >> 6, rr = tid >> 4, gg = tid & 15;
    __shared__ int sco[28], scnt[27], sgo[27];
    __shared__ unsigned short Ash[32 * AROW];
    __shared__ unsigned short Osh[32 * AROW];
    if (tid < 28) sco[tid] = hdr[32 + tid];
    if (tid < 27) { scnt[tid] = hdr[tid]; sgo[tid] = hdr[64 + tid]; }
    __syncthreads();
    const int tot = sco[27];
    for (int t = blockIdx.x; t < tot; t += gridDim.x) {
        int lo = 0, hi = 26;
        while (lo < hi) { int mid = (lo + hi + 1) >> 1; if (sco[mid] <= t) lo = mid; else hi = mid - 1; }
        const int k = lo, c = t - sco[k], cntk = scnt[k];
        const int srow = c * 32;
        const size_t gbase = (size_t)(sgo[k] + srow) * C;
#pragma unroll
        for (int h = 0; h < 2; ++h) {
            int row = srow + h * 16 + rr;
            uint4 pk = {0u, 0u, 0u, 0u};
            if (row < cntk) {
                int j = pairs[(size_t)k * NN + row];
                pk = *reinterpret_cast<const uint4*>(xh + (size_t)j * C + gg * 8);
            }
            *reinterpret_cast<uint4*>(&Ash[(h * 16 + rr) * AROW + gg * 8]) = pk;
        }
        __syncthreads();
        f32x4 a00 = {0.f,0.f,0.f,0.f}, a01 = {0.f,0.f,0.f,0.f};
        f32x4 a10 = {0.f,0.f,0.f,0.f}, a11 = {0.f,0.f,0.f,0.f};
        const unsigned short* ar0 = &Ash[(l & 15) * AROW + (l >> 4) * 8];
        const unsigned short* ar1 = &Ash[(16 + (l & 15)) * AROW + (l >> 4) * 8];
#pragma unroll
        for (int ks = 0; ks < 4; ++ks) {
            bfx8 b0 = Wf[((k * 4 + ks) * 8 + 2 * w) * 64 + l];
            bfx8 b1 = Wf[((k * 4 + ks) * 8 + 2 * w + 1) * 64 + l];
            bfx8 f0 = *reinterpret_cast<const bfx8*>(ar0 + ks * 32);
            bfx8 f1 = *reinterpret_cast<const bfx8*>(ar1 + ks * 32);
            a00 = __builtin_amdgcn_mfma_f32_16x16x32_bf16(f0, b0, a00, 0, 0, 0);
            a01 = __builtin_amdgcn_mfma_f32_16x16x32_bf16(f0, b1, a01, 0, 0, 0);
            a10 = __builtin_amdgcn_mfma_f32_16x16x32_bf16(f1, b0, a10, 0, 0, 0);
            a11 = __builtin_amdgcn_mfma_f32_16x16x32_bf16(f1, b1, a11, 0, 0, 0);
        }
#pragma unroll
        for (int r = 0; r < 4; ++r) {
            int row = (l >> 4) * 4 + r;
            Osh[row * AROW + w * 32 + (l & 15)]        = bf1(a00[r]);
            Osh[row * AROW + w * 32 + 16 + (l & 15)]   = bf1(a01[r]);
            Osh[(16 + row) * AROW + w * 32 + (l & 15)] = bf1(a10[r]);
            Osh[(16 + row) * AROW + w * 32 + 16 + (l & 15)] = bf1(a11[r]);
        }
        __syncthreads();
#pragma unroll
        for (int h = 0; h < 2; ++h) {
            int row = h * 16 + rr;
            uint4 v = *reinterpret_cast<uint4*>(&Osh[row * AROW + gg * 8]);
            *reinterpret_cast<uint4*>(&g[gbase + (size_t)row * C + gg * 8]) = v;
        }
        __syncthreads();
    }
}

// ---------------------------------------------------------------------------
// convC: out[i] = sum over valid taps of g rows (bf16 out) + fused BN stats.
// ---------------------------------------------------------------------------
__global__ __launch_bounds__(256) void convC(const unsigned short* __restrict__ g, const int* __restrict__ slotmap,
                                             const int* __restrict__ hdr, const unsigned* __restrict__ maskbuf,
                                             unsigned short* __restrict__ outh, float* __restrict__ psb,
                                             float* __restrict__ pqb) {
    const int tid = threadIdx.x, p = tid >> 4, gg = tid & 15, c0 = gg * 8;
    const int i = blockIdx.x * 16 + p;
    __shared__ int sgo[27];
    __shared__ float outt[16 * 132];
    if (tid < 27) sgo[tid] = hdr[64 + tid];
    __syncthreads();
    unsigned m = maskbuf[i];
    float acc[8] = {0.f,0.f,0.f,0.f,0.f,0.f,0.f,0.f};
    while (m) {
        int k = (int)__builtin_ctz(m); m &= m - 1;
        int slot = slotmap[(size_t)k * NN + i];
        const unsigned short* gr = &g[(size_t)(sgo[k] + slot) * C + c0];
        uint4 u = *reinterpret_cast<const uint4*>(gr);
        acc[0] += __uint_as_float(u.x << 16); acc[1] += __uint_as_float(u.x & 0xffff0000u);
        acc[2] += __uint_as_float(u.y << 16); acc[3] += __uint_as_float(u.y & 0xffff0000u);
        acc[4] += __uint_as_float(u.z << 16); acc[5] += __uint_as_float(u.z & 0xffff0000u);
        acc[6] += __uint_as_float(u.w << 16); acc[7] += __uint_as_float(u.w & 0xffff0000u);
    }
#pragma unroll
    for (int c2 = 0; c2 < 8; ++c2) outt[p * 132 + c0 + c2] = acc[c2];
    uint4 pk;
    pk.x = pack_bf2(acc[0], acc[1]); pk.y = pack_bf2(acc[2], acc[3]);
    pk.z = pack_bf2(acc[4], acc[5]); pk.w = pack_bf2(acc[6], acc[7]);
    *reinterpret_cast<uint4*>(&outh[(size_t)i * C + c0]) = pk;
    __syncthreads();
    if (tid < 128) {
        float s = 0.f, q = 0.f;
#pragma unroll
        for (int r = 0; r < 16; ++r) { float v = outt[r * 132 + tid]; s += v; q += v * v; }
        psb[(size_t)blockIdx.x * C + tid] = s;
        pqb[(size_t)blockIdx.x * C + tid] = q;
    }
}

// ---------------------------------------------------------------------------
// Fused BN stats (single kernel, 64 blocks, ticket last-block final).
// 64-block fences over ~3MB of partials are cheap; NOT at 1000+ blocks (R9).
// ---------------------------------------------------------------------------
__global__ __launch_bounds__(256) void statsF128(const float* __restrict__ psb, const float* __restrict__ pqb,
                                                 int rows,
                                                 float* __restrict__ ps2, float* __restrict__ pq2,
                                                 const float* __restrict__ g, const float* __restrict__ b,
                                                 float* __restrict__ a, float* __restrict__ cc,
                                                 int* __restrict__ ticket) {
    const int tid = threadIdx.x, ch = tid & 127, half = tid >> 7;
    float s = 0.f, q = 0.f;
    for (int i = blockIdx.x * 2 + half; i < rows; i += 128) {
        s += psb[(size_t)i * C + ch];
        q += pqb[(size_t)i * C + ch];
    }
    __shared__ float ls[256], lq[256];
    __shared__ int amlast;
    ls[tid] = s; lq[tid] = q;
    __syncthreads();
    if (tid < 128) {
        ps2[blockIdx.x * C + ch] = ls[tid] + ls[tid + 128];
        pq2[blockIdx.x * C + ch] = lq[tid] + lq[tid + 128];
    }
    __threadfence();
    __syncthreads();
    if (tid == 0) amlast = (atomicAdd(ticket, 1) == 63) ? 1 : 0;
    __syncthreads();
    if (!amlast) return;
    __threadfence();
    if (tid < 128) {
        float ss = 0.f, qq = 0.f;
        for (int i = 0; i < 64; ++i) { ss += ps2[i * C + ch]; qq += pq2[i * C + ch]; }
        float m = ss / (float)NN;
        float var = fmaxf(qq / (float)NN - m * m, 0.f);
        float rs = rsqrtf(var + 1e-5f);
        float av = g[ch] * rs;
        a[ch] = av;
        cc[ch] = b[ch] - m * av;
    }
}

__global__ __launch_bounds__(256) void statsF16(const float* __restrict__ buf,
                                                float* __restrict__ ps2, float* __restrict__ pq2,
                                                const float* __restrict__ g, const float* __restrict__ b,
                                                float* __restrict__ a, float* __restrict__ cc,
                                                int* __restrict__ ticket) {
    const int tid = threadIdx.x, ch = tid & 15, grp = tid >> 4;
    float s = 0.f, q = 0.f;
    for (int i = blockIdx.x * 16 + grp; i < NN; i += 64 * 16) {
        float val = buf[(size_t)i * VEC + ch];
        s += val; q += val * val;
    }
    __shared__ float ls[256], lq[256];
    __shared__ int amlast;
    ls[tid] = s; lq[tid] = q;
    __syncthreads();
    if (tid < 16) {
        float ss = 0.f, qq = 0.f;
        for (int g2 = 0; g2 < 16; ++g2) { ss += ls[g2 * 16 + ch]; qq += lq[g2 * 16 + ch]; }
        ps2[blockIdx.x * VEC + ch] = ss; pq2[blockIdx.x * VEC + ch] = qq;
    }
    __threadfence();
    __syncthreads();
    if (tid == 0) amlast = (atomicAdd(ticket, 1) == 63) ? 1 : 0;
    __syncthreads();
    if (!amlast) return;
    __threadfence();
    if (tid < 16) {
        float ss = 0.f, qq = 0.f;
        for (int i = 0; i < 64; ++i) { ss += ps2[i * VEC + ch]; qq += pq2[i * VEC + ch]; }
        float m = ss / (float)NN;
        float var = fmaxf(qq / (float)NN - m * m, 0.f);
        float rs = rsqrtf(var + 1e-5f);
        float av = g[ch] * rs;
        a[ch] = av;
        cc[ch] = b[ch] - m * av;
    }
}

// ---------------------------------------------------------------------------
// Dense bf16[N,128]@[128,128] MFMA matmul, 32-row tile, fused input BN+ReLU,
// bf16 output + fused fp32 BN partial stats on the output.
// ---------------------------------------------------------------------------
__global__ __launch_bounds__(256) void mm_bn_h32(const unsigned short* __restrict__ in,
                                                 const float* __restrict__ a,
                                                 const float* __restrict__ cc,
                                                 const bfx8* __restrict__ Wf,
                                                 unsigned short* __restrict__ out,
                                                 float* __restrict__ psb,
                                                 float* __restrict__ pqb) {
    const int tid = threadIdx.x, l = tid & 63, w = tid >> 6;
    const int rr = tid >> 4, gg = tid & 15;
    const size_t base = (size_t)blockIdx.x * 32;
    __shared__ unsigned short Ash[32 * AROW];
    __shared__ float outt[32 * 132];
    float4 a4 = *reinterpret_cast<const float4*>(&a[gg * 8]);
    float4 a4b = *reinterpret_cast<const float4*>(&a[gg * 8 + 4]);
    float4 c4 = *reinterpret_cast<const float4*>(&cc[gg * 8]);
    float4 c4b = *reinterpret_cast<const float4*>(&cc[gg * 8 + 4]);
#pragma unroll
    for (int h = 0; h < 2; ++h) {
        int row = h * 16 + rr;
        uint4 u = *reinterpret_cast<const uint4*>(in + (base + row) * C + gg * 8);
        float e0 = fmaxf(fmaf(__uint_as_float(u.x << 16),        a4.x,  c4.x), 0.f);
        float e1 = fmaxf(fmaf(__uint_as_float(u.x & 0xffff0000u), a4.y,  c4.y), 0.f);
        float e2 = fmaxf(fmaf(__uint_as_float(u.y << 16),        a4.z,  c4.z), 0.f);
        float e3 = fmaxf(fmaf(__uint_as_float(u.y & 0xffff0000u), a4.w,  c4.w), 0.f);
        float e4 = fmaxf(fmaf(__uint_as_float(u.z << 16),        a4b.x, c4b.x), 0.f);
        float e5 = fmaxf(fmaf(__uint_as_float(u.z & 0xffff0000u), a4b.y, c4b.y), 0.f);
        float e6 = fmaxf(fmaf(__uint_as_float(u.w << 16),        a4b.z, c4b.z), 0.f);
        float e7 = fmaxf(fmaf(__uint_as_float(u.w & 0xffff0000u), a4b.w, c4b.w), 0.f);
        u.x = pack_bf2(e0, e1); u.y = pack_bf2(e2, e3);
        u.z = pack_bf2(e4, e5); u.w = pack_bf2(e6, e7);
        *reinterpret_cast<uint4*>(&Ash[row * AROW + gg * 8]) = u;
    }
    __syncthreads();
    f32x4 a00 = {0.f,0.f,0.f,0.f}, a01 = {0.f,0.f,0.f,0.f};
    f32x4 a10 = {0.f,0.f,0.f,0.f}, a11 = {0.f,0.f,0.f,0.f};
    const unsigned short* ar0 = &Ash[(l & 15) * AROW + (l >> 4) * 8];
    const unsigned short* ar1 = &Ash[(16 + (l & 15)) * AROW + (l >> 4) * 8];
#pragma unroll
    for (int ks = 0; ks < 4; ++ks) {
        bfx8 b0 = Wf[(ks * 8 + 2 * w) * 64 + l];
        bfx8 b1 = Wf[(ks * 8 + 2 * w + 1) * 64 + l];
        bfx8 f0 = *reinterpret_cast<const bfx8*>(ar0 + ks * 32);
        bfx8 f1 = *reinterpret_cast<const bfx8*>(ar1 + ks * 32);
        a00 = __builtin_amdgcn_mfma_f32_16x16x32_bf16(f0, b0, a00, 0, 0, 0);
        a01 = __builtin_amdgcn_mfma_f32_16x16x32_bf16(f0, b1, a01, 0, 0, 0);
        a10 = __builtin_amdgcn_mfma_f32_16x16x32_bf16(f1, b0, a10, 0, 0, 0);
        a11 = __builtin_amdgcn_mfma_f32_16x16x32_bf16(f1, b1, a11, 0, 0, 0);
    }
#pragma unroll
    for (int r = 0; r < 4; ++r) {
        int row = (l >> 4) * 4 + r;
        outt[row * 132 + w * 32 + (l & 15)]        = a00[r];
        outt[row * 132 + w * 32 + 16 + (l & 15)]   = a01[r];
        outt[(16 + row) * 132 + w * 32 + (l & 15)] = a10[r];
        outt[(16 + row) * 132 + w * 32 + 16 + (l & 15)] = a11[r];
    }
    __syncthreads();
#pragma unroll
    for (int h = 0; h < 2; ++h) {
        int row = h * 16 + rr;
        float4 v0 = *reinterpret_cast<float4*>(&outt[row * 132 + gg * 8]);
        float4 v1 = *reinterpret_cast<float4*>(&outt[row * 132 + gg * 8 + 4]);
        uint4 pk;
        pk.x = pack_bf2(v0.x, v0.y); pk.y = pack_bf2(v0.z, v0.w);
        pk.z = pack_bf2(v1.x, v1.y); pk.w = pack_bf2(v1.z, v1.w);
        *reinterpret_cast<uint4*>(&out[(base + row) * C + gg * 8]) = pk;
    }
    if (tid < 128) {
        float s = 0.f, q = 0.f;
#pragma unroll
        for (int r = 0; r < 32; ++r) { float v = outt[r * 132 + tid]; s += v; q += v * v; }
        psb[(size_t)blockIdx.x * C + tid] = s;
        pqb[(size_t)blockIdx.x * C + tid] = q;
    }
}

// ---------------------------------------------------------------------------
// q = xh(bf16) @ q_w  ([N,128] @ [128,16]) fp32 accumulate
// ---------------------------------------------------------------------------
__global__ __launch_bounds__(256) void qmmh(const unsigned short* __restrict__ xh,
                                            const float* __restrict__ qw,
                                            float* __restrict__ outq) {
    const int v = threadIdx.x & 15, p = threadIdx.x >> 4;
    const size_t i = (size_t)blockIdx.x * 16 + p;
    float acc = 0.f;
    for (int cin0 = 0; cin0 < C; cin0 += 8) {
        uint4 u = *reinterpret_cast<const uint4*>(xh + i * C + cin0);
        acc += __uint_as_float(u.x << 16)         * qw[(cin0 + 0) * VEC + v]
             + __uint_as_float(u.x & 0xffff0000u) * qw[(cin0 + 1) * VEC + v]
             + __uint_as_float(u.y << 16)         * qw[(cin0 + 2) * VEC + v]
             + __uint_as_float(u.y & 0xffff0000u) * qw[(cin0 + 3) * VEC + v]
             + __uint_as_float(u.z << 16)         * qw[(cin0 + 4) * VEC + v]
             + __uint_as_float(u.z & 0xffff0000u) * qw[(cin0 + 5) * VEC + v]
             + __uint_as_float(u.w << 16)         * qw[(cin0 + 6) * VEC + v]
             + __uint_as_float(u.w & 0xffff0000u) * qw[(cin0 + 7) * VEC + v];
    }
    outq[i * VEC + v] = acc;
}

// ---------------------------------------------------------------------------
// Fused attention + OUTPUT 1x1 CONV: 16 points / 256 threads — R11-measured
// best shape (81us, 44 VGPR, 50% occ). Serial 16-thread compaction, unpacked
// sj/sk, raw[] aliased into outt[] (disjoint lifetimes).
// ---------------------------------------------------------------------------
__global__ __launch_bounds__(256) void attn_out(const unsigned short* __restrict__ vraw,
                                                const float* __restrict__ a2,
                                                const float* __restrict__ c2,
                                                const float* __restrict__ qraw,
                                                const float* __restrict__ aq,
                                                const float* __restrict__ cq,
                                                const int* __restrict__ nA,
                                                const int* __restrict__ nB,
                                                const int* __restrict__ nC,
                                                const float* __restrict__ cb0,
                                                const float* __restrict__ cb1,
                                                const float* __restrict__ cb2,
                                                const bfx8* __restrict__ Wf,
                                                unsigned short* __restrict__ outh,
                                                float* __restrict__ psb,
                                                float* __restrict__ pqb) {
    const int tid = threadIdx.x, l = tid & 63, w = tid >> 6;
    const int base = blockIdx.x * 16;
    __shared__ float outt[16 * 132];          // phase A: raw indices; phase E: fp32 out tile
    int* raw = (int*)outt;                    // raw[p*41+k], 2624B < 8448B
    __shared__ int sj[16][44];
    __shared__ short sk[16][44];
    __shared__ short sb[16][4];
    __shared__ float sattn[16][16][3];
    __shared__ unsigned short Ash[16 * AROW];

    for (int t = tid; t < 656; t += 256) {
        int k = t >> 4, p = t & 15;
        int i = base + p;
        int j;
        if (k < 7)       j = nA[(size_t)k * NN + i];
        else if (k < 34) j = nB[(size_t)(k - 7) * NN + i];
        else             j = nC[(size_t)(k - 34) * NN + i];
        raw[p * 41 + k] = j;
    }
    __syncthreads();
    if (tid < 16) {
        int p = tid, n = 0;
#pragma unroll
        for (int k = 0; k < 7; ++k) { int j = raw[p * 41 + k]; if (j >= 0) { sj[p][n] = j; sk[p][n] = (short)k; ++n; } }
        int b0 = n;
#pragma unroll
        for (int k = 7; k < 34; ++k) { int j = raw[p * 41 + k]; if (j >= 0) { sj[p][n] = j; sk[p][n] = (short)(k - 7); ++n; } }
        int b1 = n;
#pragma unroll
        for (int k = 34; k < 41; ++k) { int j = raw[p * 41 + k]; if (j >= 0) { sj[p][n] = j; sk[p][n] = (short)(k - 34); ++n; } }
        sb[p][0] = (short)b0; sb[p][1] = (short)b1; sb[p][2] = (short)n;
    }
    __syncthreads();
    {   // scores + softmax: 16p x 16v, q-BN applied inline
        int p = tid >> 4, v = tid & 15;
        int b0 = sb[p][0], b1 = sb[p][1], b2 = sb[p][2];
        float av = aq[v], cv = cq[v];
        float qi = fmaxf(fmaf(qraw[(size_t)(base + p) * VEC + v], av, cv), 0.f);
        float a0 = 0.f, a1 = 0.f, a2s = 0.f;
        for (int s = 0; s < b0; ++s) a0 += fmaxf(fmaf(qraw[(size_t)sj[p][s] * VEC + v], av, cv), 0.f);
        for (int s = b0; s < b1; ++s) a1 += fmaxf(fmaf(qraw[(size_t)sj[p][s] * VEC + v], av, cv), 0.f);
        for (int s = b1; s < b2; ++s) a2s += fmaxf(fmaf(qraw[(size_t)sj[p][s] * VEC + v], av, cv), 0.f);
        float s0 = qi * a0 / (float)(b0 > 0 ? b0 : 1);
        float s1 = qi * a1 / (float)(b1 - b0 > 0 ? b1 - b0 : 1);
        float s2 = qi * a2s / (float)(b2 - b1 > 0 ? b2 - b1 : 1);
        float mx = fmaxf(s0, fmaxf(s1, s2));
        float e0 = __expf(s0 - mx), e1 = __expf(s1 - mx), e2 = __expf(s2 - mx);
        float inv = 1.f / (e0 + e1 + e2);
        sattn[p][v][0] = e0 * inv; sattn[p][v][1] = e1 * inv; sattn[p][v][2] = e2 * inv;
    }
    __syncthreads();
    {   // channelwise mix: 16p x 16 lanes x 8 channels, v-BN inline,
        // THREE static expert loops (A0/A1/A2 stay in VGPRs - rule #20)
        int p = tid >> 4, g = tid & 15, c0 = g * 8;
        int b0 = sb[p][0], b1 = sb[p][1], b2 = sb[p][2];
        float4 va = *reinterpret_cast<const float4*>(&a2[c0]);
        float4 vab = *reinterpret_cast<const float4*>(&a2[c0 + 4]);
        float4 vc = *reinterpret_cast<const float4*>(&c2[c0]);
        float4 vcb = *reinterpret_cast<const float4*>(&c2[c0 + 4]);
        float A0[8], A1[8], A2[8];
#pragma unroll
        for (int c = 0; c < 8; ++c) { A0[c] = 0.f; A1[c] = 0.f; A2[c] = 0.f; }
        for (int s = 0; s < b0; ++s) {
            int j = sj[p][s], k = sk[p][s];
            uint4 u = *reinterpret_cast<const uint4*>(vraw + (size_t)j * C + c0);
            float4 ca = *reinterpret_cast<const float4*>(&cb0[k * C + c0]);
            float4 cb = *reinterpret_cast<const float4*>(&cb0[k * C + c0 + 4]);
            A0[0] = fmaf(ca.x, fmaxf(fmaf(__uint_as_float(u.x << 16),        va.x,  vc.x), 0.f), A0[0]);
            A0[1] = fmaf(ca.y, fmaxf(fmaf(__uint_as_float(u.x & 0xffff0000u), va.y,  vc.y), 0.f), A0[1]);
            A0[2] = fmaf(ca.z, fmaxf(fmaf(__uint_as_float(u.y << 16),        va.z,  vc.z), 0.f), A0[2]);
            A0[3] = fmaf(ca.w, fmaxf(fmaf(__uint_as_float(u.y & 0xffff0000u), va.w,  vc.w), 0.f), A0[3]);
            A0[4] = fmaf(cb.x, fmaxf(fmaf(__uint_as_float(u.z << 16),        vab.x, vcb.x), 0.f), A0[4]);
            A0[5] = fmaf(cb.y, fmaxf(fmaf(__uint_as_float(u.z & 0xffff0000u), vab.y, vcb.y), 0.f), A0[5]);
            A0[6] = fmaf(cb.z, fmaxf(fmaf(__uint_as_float(u.w << 16),        vab.z, vcb.z), 0.f), A0[6]);
            A0[7] = fmaf(cb.w, fmaxf(fmaf(__uint_as_float(u.w & 0xffff0000u), vab.w, vcb.w), 0.f), A0[7]);
        }
        for (int s = b0; s < b1; ++s) {
            int j = sj[p][s], k = sk[p][s];
            uint4 u = *reinterpret_cast<const uint4*>(vraw + (size_t)j * C + c0);
            float4 ca = *reinterpret_cast<const float4*>(&cb1[k * C + c0]);
            float4 cb = *reinterpret_cast<const float4*>(&cb1[k * C + c0 + 4]);
            A1[0] = fmaf(ca.x, fmaxf(fmaf(__uint_as_float(u.x << 16),        va.x,  vc.x), 0.f), A1[0]);
            A1[1] = fmaf(ca.y, fmaxf(fmaf(__uint_as_float(u.x & 0xffff0000u), va.y,  vc.y), 0.f), A1[1]);
            A1[2] = fmaf(ca.z, fmaxf(fmaf(__uint_as_float(u.y << 16),        va.z,  vc.z), 0.f), A1[2]);
            A1[3] = fmaf(ca.w, fmaxf(fmaf(__uint_as_float(u.y & 0xffff0000u), va.w,  vc.w), 0.f), A1[3]);
            A1[4] = fmaf(cb.x, fmaxf(fmaf(__uint_as_float(u.z << 16),        vab.x, vcb.x), 0.f), A1[4]);
            A1[5] = fmaf(cb.y, fmaxf(fmaf(__uint_as_float(u.z & 0xffff0000u), vab.y, vcb.y), 0.f), A1[5]);
            A1[6] = fmaf(cb.z, fmaxf(fmaf(__uint_as_float(u.w << 16),        vab.z, vcb.z), 0.f), A1[6]);
            A1[7] = fmaf(cb.w, fmaxf(fmaf(__uint_as_float(u.w & 0xffff0000u), vab.w, vcb.w), 0.f), A1[7]);
        }
        for (int s = b1; s < b2; ++s) {
            int j = sj[p][s], k = sk[p][s];
            uint4 u = *reinterpret_cast<const uint4*>(vraw + (size_t)j * C + c0);
            float4 ca = *reinterpret_cast<const float4*>(&cb2[k * C + c0]);
            float4 cb = *reinterpret_cast<const float4*>(&cb2[k * C + c0 + 4]);
            A2[0] = fmaf(ca.x, fmaxf(fmaf(__uint_as_float(u.x << 16),        va.x,  vc.x), 0.f), A2[0]);
            A2[1] = fmaf(ca.y, fmaxf(fmaf(__uint_as_float(u.x & 0xffff0000u), va.y,  vc.y), 0.f), A2[1]);
            A2[2] = fmaf(ca.z, fmaxf(fmaf(__uint_as_float(u.y << 16),        va.z,  vc.z), 0.f), A2[2]);
            A2[3] = fmaf(ca.w, fmaxf(fmaf(__uint_as_float(u.y & 0xffff0000u), va.w,  vc.w), 0.f), A2[3]);
            A2[4] = fmaf(cb.x, fmaxf(fmaf(__uint_as_float(u.z << 16),        vab.x, vcb.x), 0.f), A2[4]);
            A2[5] = fmaf(cb.y, fmaxf(fmaf(__uint_as_float(u.z & 0xffff0000u), vab.y, vcb.y), 0.f), A2[5]);
            A2[6] = fmaf(cb.z, fmaxf(fmaf(__uint_as_float(u.w << 16),        vab.z, vcb.z), 0.f), A2[6]);
            A2[7] = fmaf(cb.w, fmaxf(fmaf(__uint_as_float(u.w & 0xffff0000u), vab.w, vcb.w), 0.f), A2[7]);
        }
        float w0 = sattn[p][g][0], w1 = sattn[p][g][1], w2 = sattn[p][g][2];
        float o[8];
#pragma unroll
        for (int c = 0; c < 8; ++c) o[c] = w0 * A0[c] + w1 * A1[c] + w2 * A2[c];
        uint4 pk;
        pk.x = pack_bf2(o[0], o[1]); pk.y = pack_bf2(o[2], o[3]);
        pk.z = pack_bf2(o[4], o[5]); pk.w = pack_bf2(o[6], o[7]);
        *reinterpret_cast<uint4*>(&Ash[p * AROW + c0]) = pk;   // stage mix tile
    }
    __syncthreads();   // raw done; outt reused below
    // output 1x1 conv: 16-row MFMA tile against outf
    {
        f32x4 acc0 = {0.f, 0.f, 0.f, 0.f};
        f32x4 acc1 = {0.f, 0.f, 0.f, 0.f};
        const unsigned short* arow = &Ash[(l & 15) * AROW + (l >> 4) * 8];
#pragma unroll
        for (int ks = 0; ks < 4; ++ks) {
            bfx8 af = *reinterpret_cast<const bfx8*>(arow + ks * 32);
            bfx8 b0 = Wf[(ks * 8 + 2 * w) * 64 + l];
            bfx8 b1 = Wf[(ks * 8 + 2 * w + 1) * 64 + l];
            acc0 = __builtin_amdgcn_mfma_f32_16x16x32_bf16(af, b0, acc0, 0, 0, 0);
            acc1 = __builtin_amdgcn_mfma_f32_16x16x32_bf16(af, b1, acc1, 0, 0, 0);
        }
#pragma unroll
        for (int r = 0; r < 4; ++r) {
            int row = (l >> 4) * 4 + r;
            outt[row * 132 + w * 32 + (l & 15)] = acc0[r];
            outt[row * 132 + w * 32 + 16 + (l & 15)] = acc1[r];
        }
    }
    __syncthreads();
    {
        int rr = tid >> 4, gg = tid & 15;
        float4 v0 = *reinterpret_cast<float4*>(&outt[rr * 132 + gg * 8]);
        float4 v1 = *reinterpret_cast<float4*>(&outt[rr * 132 + gg * 8 + 4]);
        uint4 pk;
        pk.x = pack_bf2(v0.x, v0.y); pk.y = pack_bf2(v0.z, v0.w);
        pk.z = pack_bf2(v1.x, v1.y); pk.w = pack_bf2(v1.z, v1.w);
        *reinterpret_cast<uint4*>(&outh[(size_t)(base + rr) * C + gg * 8]) = pk;
    }
    if (tid < 128) {
        float s = 0.f, q = 0.f;
#pragma unroll
        for (int r = 0; r < 16; ++r) { float v = outt[r * 132 + tid]; s += v; q += v * v; }
        psb[(size_t)blockIdx.x * C + tid] = s;
        pqb[(size_t)blockIdx.x * C + tid] = q;
    }
}

// out = relu(bf16buf*a + c) + xh   (fp32 out, bf16 residual read)
__global__ __launch_bounds__(256) void final_bn_res_h(const unsigned short* __restrict__ buf,
                                                      const float* __restrict__ a,
                                                      const float* __restrict__ cc,
                                                      const unsigned short* __restrict__ xh,
                                                      float* __restrict__ out) {
    const int total8 = NN * C / 8;
    for (int t = blockIdx.x * 256 + threadIdx.x; t < total8; t += gridDim.x * 256) {
        int ch = (t * 8) & 127;
        uint4 u = *reinterpret_cast<const uint4*>(buf + (size_t)t * 8);
        uint4 xu = *reinterpret_cast<const uint4*>(xh + (size_t)t * 8);
        float4 a4 = *reinterpret_cast<const float4*>(&a[ch]);
        float4 a4b = *reinterpret_cast<const float4*>(&a[ch + 4]);
        float4 c4 = *reinterpret_cast<const float4*>(&cc[ch]);
        float4 c4b = *reinterpret_cast<const float4*>(&cc[ch + 4]);
        float4 o0, o1;
        o0.x = fmaxf(fmaf(__uint_as_float(u.x << 16),        a4.x,  c4.x), 0.f) + __uint_as_float(xu.x << 16);
        o0.y = fmaxf(fmaf(__uint_as_float(u.x & 0xffff0000u), a4.y,  c4.y), 0.f) + __uint_as_float(xu.x & 0xffff0000u);
        o0.z = fmaxf(fmaf(__uint_as_float(u.y << 16),        a4.z,  c4.z), 0.f) + __uint_as_float(xu.y << 16);
        o0.w = fmaxf(fmaf(__uint_as_float(u.y & 0xffff0000u), a4.w,  c4.w), 0.f) + __uint_as_float(xu.y & 0xffff0000u);
        o1.x = fmaxf(fmaf(__uint_as_float(u.z << 16),        a4b.x, c4b.x), 0.f) + __uint_as_float(xu.z << 16);
        o1.y = fmaxf(fmaf(__uint_as_float(u.z & 0xffff0000u), a4b.y, c4b.y), 0.f) + __uint_as_float(xu.z & 0xffff0000u);
        o1.z = fmaxf(fmaf(__uint_as_float(u.w << 16),        a4b.z, c4b.z), 0.f) + __uint_as_float(xu.w << 16);
        o1.w = fmaxf(fmaf(__uint_as_float(u.w & 0xffff0000u), a4b.w, c4b.w), 0.f) + __uint_as_float(xu.w & 0xffff0000u);
        *reinterpret_cast<float4*>(out + (size_t)t * 8) = o0;
        *reinterpret_cast<float4*>(out + (size_t)t * 8 + 4) = o1;
    }
}

extern "C" void kernel_launch(void* const* d_in, const int* in_sizes, int n_in,
                              void* d_out, int out_size, void* d_ws, size_t ws_size,
                              hipStream_t stream) {
    (void)in_sizes; (void)n_in; (void)out_size; (void)ws_size;
    const float* x    = (const float*)d_in[0];
    const float* v1_w = (const float*)d_in[1];
    const float* v1_g = (const float*)d_in[2];
    const float* v1_b = (const float*)d_in[3];
    const float* v2_w = (const float*)d_in[4];
    const float* v2_g = (const float*)d_in[5];
    const float* v2_b = (const float*)d_in[6];
    const float* q_w  = (const float*)d_in[7];
    const float* q_g  = (const float*)d_in[8];
    const float* q_b  = (const float*)d_in[9];
    const float* cb0  = (const float*)d_in[10];
    const float* cb1  = (const float*)d_in[11];
    const float* cb2  = (const float*)d_in[12];
    const float* out_w = (const float*)d_in[13];
    const float* out_g = (const float*)d_in[14];
    const float* out_b = (const float*)d_in[15];
    const int* nbrA = (const int*)d_in[16];   // cross2, K=7
    const int* nbrB = (const int*)d_in[17];   // cube,  K=27
    const int* nbrC = (const int*)d_in[18];   // cross3, K=7
    float* out = (float*)d_out;

    float* w = (float*)d_ws;
    unsigned short* bufAh = (unsigned short*)w;                // NN*C ushorts
    float* r1 = w + (size_t)NN * C / 2;
    // region1 (conv-stage) aliased by later {bufBh, bufQ}:
    unsigned short* g = (unsigned short*)r1;                   // GCAP*C ushorts
    int* slotmap = (int*)(r1 + 15360000);
    int* pairs   = (int*)(r1 + 15360000 + 2700000);
    unsigned short* bufBh = (unsigned short*)r1;               // NN*C ushorts
    float* bufQ = r1 + 6400000;                                // NN*VEC floats
    size_t o = (size_t)NN * C / 2 + 20760000;
    unsigned short* xh = (unsigned short*)(w + o); o += (size_t)NN * C / 2;
    float* psb  = w + o; o += (size_t)6250 * C;
    float* pqb  = w + o; o += (size_t)6250 * C;
    float* ps2  = w + o; o += 64 * C;
    float* pq2  = w + o; o += 64 * C;
    float* ps16 = w + o; o += 64 * VEC;
    float* pq16 = w + o; o += 64 * VEC;
    float* a1 = w + o; o += C;  float* c1 = w + o; o += C;
    float* a2 = w + o; o += C;  float* c2 = w + o; o += C;
    float* ao = w + o; o += C;  float* co = w + o; o += C;
    float* aq = w + o; o += VEC; float* cq = w + o; o += VEC;
    unsigned short* v1f = (unsigned short*)(w + o); o += (27 * 16384) / 2;
    unsigned short* v2f = (unsigned short*)(w + o); o += 16384 / 2;
    unsigned short* outf = (unsigned short*)(w + o); o += 16384 / 2;
    int* hdr = (int*)(w + o); o += 128;      // [96..99] = stat tickets
    unsigned* maskbuf = (unsigned*)(w + o); o += NN;

    hipMemsetAsync(hdr, 0, (size_t)(128 + NN) * sizeof(int), stream);
    prep<<<2880, 256, 0, stream>>>(v1_w, v2_w, out_w, x, v1f, v2f, outf, xh);

    // conv1 (cube-27): compaction + prefix + dense GEMM + scatter-sum
    compactA<<<27 * 49, 256, 0, stream>>>(nbrB, hdr, slotmap, pairs, maskbuf);
    prefixA2<<<1, 64, 0, stream>>>(hdr);
    convB<<<2048, 256, 0, stream>>>(xh, pairs, hdr, (const bfx8*)v1f, g);
    convC<<<NN / 16, 256, 0, stream>>>(g, slotmap, hdr, maskbuf, bufAh, psb, pqb);
    statsF128<<<64, 256, 0, stream>>>(psb, pqb, 6250, ps2, pq2, v1_g, v1_b, a1, c1, hdr + 96);

    // v2 1x1 conv (fused input BN+ReLU) -> bufBh raw (g/slotmap/pairs dead)
    mm_bn_h32<<<NN / 32, 256, 0, stream>>>(bufAh, a1, c1, (const bfx8*)v2f, bufBh, psb, pqb);
    statsF128<<<64, 256, 0, stream>>>(psb, pqb, 3125, ps2, pq2, v2_g, v2_b, a2, c2, hdr + 97);

    // query branch (bf16 x input; BN fused into attn)
    qmmh<<<NN / 16, 256, 0, stream>>>(xh, q_w, bufQ);
    statsF16<<<64, 256, 0, stream>>>(bufQ, ps16, pq16, q_g, q_b, aq, cq, hdr + 98);

    // fused expert convs + attention mix + OUTPUT 1x1 conv -> bufAh raw
    attn_out<<<NN / 16, 256, 0, stream>>>(bufBh, a2, c2, bufQ, aq, cq,
                                          nbrA, nbrB, nbrC, cb0, cb1, cb2,
                                          (const bfx8*)outf, bufAh, psb, pqb);
    statsF128<<<64, 256, 0, stream>>>(psb, pqb, 6250, ps2, pq2, out_g, out_b, ao, co, hdr + 99);

    // final BN + residual (bf16 residual read)
    final_bn_res_h<<<2048, 256, 0, stream>>>(bufAh, ao, co, xh, out);
}